// Round 1
// baseline (1750.750 us; speedup 1.0000x reference)
//
#include <hip/hip_runtime.h>
#include <hip/hip_bf16.h>
#include <math.h>

#define S_LEN 2048
#define BATCH 2
#define DMODEL 1024
#define NH 16
#define NKV 4
#define HDIM 64
#define EPS 1e-5f
#define ATT_SCALE 0.03125f   // D**-0.5 = 1/32 (reference uses full-D scale)
#define MROWS (S_LEN*BATCH)  // 4096

// ---------------- RMSNorm: one block per row, D=1024 = 256 lanes * float4 ----
__global__ __launch_bounds__(256) void rmsnorm_k(const float* __restrict__ x,
                                                 const float* __restrict__ w,
                                                 float* __restrict__ o){
  size_t row = blockIdx.x;
  const float4* xr = (const float4*)(x + row * DMODEL);
  float4 v = xr[threadIdx.x];
  float ss = v.x*v.x + v.y*v.y + v.z*v.z + v.w*v.w;
  #pragma unroll
  for (int off = 32; off; off >>= 1) ss += __shfl_down(ss, off);
  __shared__ float sm[5];
  if ((threadIdx.x & 63) == 0) sm[threadIdx.x >> 6] = ss;
  __syncthreads();
  if (threadIdx.x == 0) sm[4] = rsqrtf((sm[0]+sm[1]+sm[2]+sm[3]) * (1.0f/DMODEL) + EPS);
  __syncthreads();
  float r = sm[4];
  float4 wv = ((const float4*)w)[threadIdx.x];
  float4 ov = make_float4(v.x*r*wv.x, v.y*r*wv.y, v.z*r*wv.z, v.w*r*wv.w);
  ((float4*)(o + row * DMODEL))[threadIdx.x] = ov;
}

// ---------------- concat wq|wk|wv -> [1024,1536] (and biases) ----------------
__global__ __launch_bounds__(256) void concat_qkv_k(const float* __restrict__ wq, const float* __restrict__ wk,
                                                    const float* __restrict__ wv, const float* __restrict__ bq,
                                                    const float* __restrict__ bk, const float* __restrict__ bv,
                                                    float* __restrict__ wqkv, float* __restrict__ bqkv){
  int r = blockIdx.x, t = threadIdx.x;
  float* dst = wqkv + (size_t)r * 1536;
  const float* qrow = wq + (size_t)r * 1024;
  for (int c = t; c < 1024; c += 256) dst[c] = qrow[c];
  dst[1024 + t] = wk[(size_t)r * 256 + t];
  dst[1280 + t] = wv[(size_t)r * 256 + t];
  if (r == 0){
    for (int c = t; c < 1024; c += 256) bqkv[c] = bq[c];
    bqkv[1024 + t] = bk[t];
    bqkv[1280 + t] = bv[t];
  }
}

// ---------------- fp32 GEMM: C[M,N] = A[M,K] @ W[K,N] + bias (+epilogue) -----
// 128x64 tile, BK=16, 256 threads, 8x4 per thread.
__device__ __forceinline__ float gelu_f(float x){
  return 0.5f * x * (1.0f + erff(x * 0.7071067811865475f));
}

template<int EPI>  // 0 = none, 1 = gelu, 2 = +res
__global__ __launch_bounds__(256) void gemm_k(const float* __restrict__ A, const float* __restrict__ W,
                                              const float* __restrict__ bias, const float* __restrict__ res,
                                              float* __restrict__ C, int N, int K){
  __shared__ float As[16][132];   // [k][m], pad 132 keeps float4 reads aligned + conflict-free
  __shared__ float Bs[16][68];    // [k][n]
  const int tid = threadIdx.x;
  const int tx = tid & 15, ty = tid >> 4;
  const int bm = blockIdx.y * 128, bn = blockIdx.x * 64;
  const int am = tid >> 1, akk = (tid & 1) * 8;
  const float* aP = A + (size_t)(bm + am) * K + akk;
  const int bkk = tid >> 4, bn4 = (tid & 15) * 4;
  const float* bP = W + (size_t)bkk * N + bn + bn4;
  float acc[8][4] = {};
  for (int k0 = 0; k0 < K; k0 += 16){
    float4 a0 = *(const float4*)(aP + k0);
    float4 a1 = *(const float4*)(aP + k0 + 4);
    float4 b0 = *(const float4*)(bP + (size_t)k0 * N);
    __syncthreads();
    As[akk+0][am]=a0.x; As[akk+1][am]=a0.y; As[akk+2][am]=a0.z; As[akk+3][am]=a0.w;
    As[akk+4][am]=a1.x; As[akk+5][am]=a1.y; As[akk+6][am]=a1.z; As[akk+7][am]=a1.w;
    *(float4*)&Bs[bkk][bn4] = b0;
    __syncthreads();
    #pragma unroll
    for (int kk = 0; kk < 16; ++kk){
      float4 bv = *(const float4*)&Bs[kk][tx*4];
      float4 a01 = *(const float4*)&As[kk][ty*8];
      float4 a23 = *(const float4*)&As[kk][ty*8+4];
      float a[8] = {a01.x,a01.y,a01.z,a01.w,a23.x,a23.y,a23.z,a23.w};
      float bb[4] = {bv.x,bv.y,bv.z,bv.w};
      #pragma unroll
      for (int i = 0; i < 8; ++i)
        #pragma unroll
        for (int j = 0; j < 4; ++j)
          acc[i][j] += a[i]*bb[j];
    }
  }
  float4 bi = *(const float4*)(bias + bn + tx*4);
  float bb[4] = {bi.x,bi.y,bi.z,bi.w};
  #pragma unroll
  for (int i = 0; i < 8; ++i){
    size_t row = bm + ty*8 + i;
    size_t off = row * N + bn + tx*4;
    float ov[4];
    #pragma unroll
    for (int j = 0; j < 4; ++j){
      float v = acc[i][j] + bb[j];
      if (EPI == 1) v = gelu_f(v);
      ov[j] = v;
    }
    float4 w4 = make_float4(ov[0],ov[1],ov[2],ov[3]);
    if (EPI == 2){
      float4 r4 = *(const float4*)(res + off);
      w4.x += r4.x; w4.y += r4.y; w4.z += r4.z; w4.w += r4.w;
    }
    *(float4*)(C + off) = w4;
  }
}

// ---------------- per-head RMSNorm + RoPE, one 64-lane wave per (s,b,head) ---
__global__ __launch_bounds__(64) void rope_k(const float* __restrict__ in, const float* __restrict__ w,
                                             float* __restrict__ out, int nh, int col0, int stride){
  const int s = blockIdx.x;
  const int b = blockIdx.y / nh, hh = blockIdx.y % nh;
  const int lane = threadIdx.x;
  float v = in[((size_t)s * BATCH + b) * stride + col0 + hh*64 + lane];
  float ss = v * v;
  #pragma unroll
  for (int m = 32; m; m >>= 1) ss += __shfl_xor(ss, m);
  float r = rsqrtf(ss * (1.0f/64.0f) + EPS);
  v = v * r * w[lane];
  int i = lane & 31;
  float invf = powf(10000.0f, -((float)(2*i)) * (1.0f/64.0f));
  float ang = (float)s * invf;
  float c, sn;
  sincosf(ang, &sn, &c);
  float partner = __shfl_xor(v, 32);
  float rh = (lane < 32) ? -partner : partner;  // rotate_half
  out[(((size_t)b * nh + hh) * S_LEN + s) * 64 + lane] = v * c + rh * sn;
}

// ---------------- flash attention, 64x64 tiles, fp32 -------------------------
// Q: [B,NH,S,64] (normed+roped), K: [B,NKV,S,64] (normed+roped),
// V read straight from qkvt (col 1280 + kvh*64, row stride 1536).
// Row softmax state lives in registers: a tile row = 16 contiguous lanes.
__global__ __launch_bounds__(256) void attn_k(const float* __restrict__ Q, const float* __restrict__ Kc,
                                              const float* __restrict__ QKVt, float* __restrict__ AO){
  __shared__ float Qs[64][68];
  __shared__ float KVs[64][64];   // holds K^T (as [d][c]) then V (as [c][d])
  __shared__ float Ps[64][68];
  const int qb = blockIdx.x;           // q tile 0..31
  const int bh = blockIdx.y;           // b*16 + h
  const int b = bh >> 4, h = bh & 15;
  const int kvh = h >> 2;              // GQA: repeat_interleave -> h/4
  const int tid = threadIdx.x;
  const int tx = tid & 15, ty = tid >> 4;
  const int lane = tid & 63, wvi = tid >> 6;

  const float* qp = Q + (((size_t)bh * S_LEN) + (size_t)qb*64) * 64;
  const float* kp = Kc + ((size_t)(b*NKV + kvh) * S_LEN) * 64;
  const float* vp = QKVt + 1280 + kvh*64;

  #pragma unroll
  for (int ii = 0; ii < 4; ++ii){
    int lin = tid + 256*ii;
    int r = lin >> 4, c4 = (lin & 15) * 4;
    *(float4*)&Qs[r][c4] = *(const float4*)(qp + r*64 + c4);
  }

  float o[4][4] = {};
  float m_i[4], l_i[4];
  #pragma unroll
  for (int i = 0; i < 4; ++i){ m_i[i] = -3.0e38f; l_i[i] = 0.0f; }

  for (int kt = 0; kt <= qb; ++kt){
    __syncthreads();   // prev PV done (first iter: Q load done)
    // K tile transposed into LDS: KVs[d][c] = K[kt*64+c][d]
    #pragma unroll
    for (int ii = 0; ii < 4; ++ii){
      int d4 = 4 * (wvi + 4*ii);
      float4 kvv = *(const float4*)(kp + (size_t)(kt*64 + lane)*64 + d4);
      KVs[d4+0][lane] = kvv.x; KVs[d4+1][lane] = kvv.y;
      KVs[d4+2][lane] = kvv.z; KVs[d4+3][lane] = kvv.w;
    }
    __syncthreads();
    // S = Q K^T * scale
    float s[4][4] = {};
    for (int kk = 0; kk < 64; ++kk){
      float4 bv = *(const float4*)&KVs[kk][tx*4];
      #pragma unroll
      for (int i = 0; i < 4; ++i){
        float a = Qs[ty*4+i][kk];
        s[i][0] += a*bv.x; s[i][1] += a*bv.y; s[i][2] += a*bv.z; s[i][3] += a*bv.w;
      }
    }
    const bool diag = (kt == qb);
    #pragma unroll
    for (int i = 0; i < 4; ++i)
      #pragma unroll
      for (int j = 0; j < 4; ++j){
        float vv = s[i][j] * ATT_SCALE;
        if (diag && (tx*4+j) > (ty*4+i)) vv = -1.0e30f;   // causal mask
        s[i][j] = vv;
      }
    // online softmax: row r=4*ty+i spans the 16 lanes sharing ty (in-wave)
    float alpha[4];
    #pragma unroll
    for (int i = 0; i < 4; ++i){
      float mx = fmaxf(fmaxf(s[i][0], s[i][1]), fmaxf(s[i][2], s[i][3]));
      #pragma unroll
      for (int m = 1; m <= 8; m <<= 1) mx = fmaxf(mx, __shfl_xor(mx, m));
      mx = fmaxf(mx, m_i[i]);
      alpha[i] = __expf(m_i[i] - mx);
      m_i[i] = mx;
      float rs = 0.f;
      #pragma unroll
      for (int j = 0; j < 4; ++j){ s[i][j] = __expf(s[i][j] - mx); rs += s[i][j]; }
      #pragma unroll
      for (int m = 1; m <= 8; m <<= 1) rs += __shfl_xor(rs, m);
      l_i[i] = l_i[i] * alpha[i] + rs;
    }
    #pragma unroll
    for (int i = 0; i < 4; ++i)
      *(float4*)&Ps[ty*4+i][tx*4] = make_float4(s[i][0], s[i][1], s[i][2], s[i][3]);
    __syncthreads();   // P visible; all K reads done -> safe to overwrite KVs
    // V tile: KVs[c][d] = V[kt*64+c][d]
    #pragma unroll
    for (int ii = 0; ii < 4; ++ii){
      int lin = tid + 256*ii;
      int c = lin >> 4, d4 = (lin & 15)*4;
      *(float4*)&KVs[c][d4] = *(const float4*)(vp + ((size_t)(kt*64 + c)*BATCH + b) * 1536 + d4);
    }
    __syncthreads();
    // O = O*alpha + P @ V
    #pragma unroll
    for (int i = 0; i < 4; ++i){
      o[i][0]*=alpha[i]; o[i][1]*=alpha[i]; o[i][2]*=alpha[i]; o[i][3]*=alpha[i];
    }
    for (int c = 0; c < 64; ++c){
      float4 vv = *(const float4*)&KVs[c][tx*4];
      #pragma unroll
      for (int i = 0; i < 4; ++i){
        float pp = Ps[ty*4+i][c];
        o[i][0] += pp*vv.x; o[i][1] += pp*vv.y; o[i][2] += pp*vv.z; o[i][3] += pp*vv.w;
      }
    }
  }
  // write: AO[(s*B+b)*D + h*64 + hd]  (matches reference transpose chain)
  #pragma unroll
  for (int i = 0; i < 4; ++i){
    int sg = qb*64 + ty*4 + i;
    float inv = 1.0f / l_i[i];
    float4 w4 = make_float4(o[i][0]*inv, o[i][1]*inv, o[i][2]*inv, o[i][3]*inv);
    *(float4*)(AO + ((size_t)sg * BATCH + b) * DMODEL + h*64 + tx*4) = w4;
  }
}

extern "C" void kernel_launch(void* const* d_in, const int* in_sizes, int n_in,
                              void* d_out, int out_size, void* d_ws, size_t ws_size,
                              hipStream_t stream){
  const float* x   = (const float*)d_in[0];
  const float* n1w = (const float*)d_in[1];
  const float* wq  = (const float*)d_in[2];
  const float* bq  = (const float*)d_in[3];
  const float* wk  = (const float*)d_in[4];
  const float* bk  = (const float*)d_in[5];
  const float* wv  = (const float*)d_in[6];
  const float* bv  = (const float*)d_in[7];
  const float* qnw = (const float*)d_in[8];
  const float* knw = (const float*)d_in[9];
  const float* wo  = (const float*)d_in[10];
  const float* bo  = (const float*)d_in[11];
  const float* n2w = (const float*)d_in[12];
  const float* w1  = (const float*)d_in[13];
  const float* b1  = (const float*)d_in[14];
  const float* w2  = (const float*)d_in[15];
  const float* b2  = (const float*)d_in[16];
  float* out = (float*)d_out;

  float* p = (float*)d_ws;
  float* h    = p; p += (size_t)MROWS * DMODEL;        // 4096x1024
  float* wqkv = p; p += (size_t)1024 * 1536;
  float* bqkv = p; p += 1536;
  float* qkvt = p; p += (size_t)MROWS * 1536;          // fused qkv proj out
  float* q    = p; p += (size_t)BATCH * NH  * S_LEN * 64;
  float* kbuf = p; p += (size_t)BATCH * NKV * S_LEN * 64;
  float* x1   = p; p += (size_t)MROWS * DMODEL;
  float* mid  = p; p += (size_t)MROWS * 4096;          // MLP hidden
  float* ao   = h;   // h is dead after QKV GEMM; reuse for attention output

  concat_qkv_k<<<1024, 256, 0, stream>>>(wq, wk, wv, bq, bk, bv, wqkv, bqkv);
  rmsnorm_k<<<MROWS, 256, 0, stream>>>(x, n1w, h);
  gemm_k<0><<<dim3(1536/64, MROWS/128), 256, 0, stream>>>(h, wqkv, bqkv, nullptr, qkvt, 1536, 1024);
  rope_k<<<dim3(S_LEN, BATCH*NH),  64, 0, stream>>>(qkvt, qnw, q,    NH,  0,    1536);
  rope_k<<<dim3(S_LEN, BATCH*NKV), 64, 0, stream>>>(qkvt, knw, kbuf, NKV, 1024, 1536);
  attn_k<<<dim3(S_LEN/64, BATCH*NH), 256, 0, stream>>>(q, kbuf, qkvt, ao);
  gemm_k<2><<<dim3(DMODEL/64, MROWS/128), 256, 0, stream>>>(ao, wo, bo, x, x1, DMODEL, DMODEL);
  rmsnorm_k<<<MROWS, 256, 0, stream>>>(x1, n2w, h);
  gemm_k<1><<<dim3(4096/64, MROWS/128), 256, 0, stream>>>(h, w1, b1, nullptr, mid, 4096, DMODEL);
  gemm_k<2><<<dim3(DMODEL/64, MROWS/128), 256, 0, stream>>>(mid, w2, b2, x1, out, DMODEL, 4096);
}

// Round 2
// 838.521 us; speedup vs baseline: 2.0879x; 2.0879x over previous
//
#include <hip/hip_runtime.h>
#include <hip/hip_bf16.h>
#include <math.h>

#define S_LEN 2048
#define BATCH 2
#define DMODEL 1024
#define NH 16
#define NKV 4
#define HDIM 64
#define EPS 1e-5f
#define ATT_SCALE 0.03125f
#define MROWS (S_LEN*BATCH)  // 4096

#define AS1 __attribute__((address_space(1)))
#define AS3 __attribute__((address_space(3)))

typedef __attribute__((ext_vector_type(8))) short bf8_t;   // 8 bf16 (4 VGPRs)
typedef __attribute__((ext_vector_type(4))) float f4_t;

__device__ __forceinline__ unsigned short f2bf(float f){
  __hip_bfloat16 b = __float2bfloat16(f);
  return __builtin_bit_cast(unsigned short, b);
}
__device__ __forceinline__ float gelu_f(float x){
  return 0.5f * x * (1.0f + erff(x * 0.7071067811865475f));
}

// ---------------- RMSNorm -> bf16 out: one block per row ---------------------
__global__ __launch_bounds__(256) void rmsnorm_k(const float* __restrict__ x,
                                                 const float* __restrict__ w,
                                                 __hip_bfloat16* __restrict__ o){
  size_t row = blockIdx.x;
  const float4* xr = (const float4*)(x + row * DMODEL);
  float4 v = xr[threadIdx.x];
  float ss = v.x*v.x + v.y*v.y + v.z*v.z + v.w*v.w;
  #pragma unroll
  for (int off = 32; off; off >>= 1) ss += __shfl_down(ss, off);
  __shared__ float sm[5];
  if ((threadIdx.x & 63) == 0) sm[threadIdx.x >> 6] = ss;
  __syncthreads();
  if (threadIdx.x == 0) sm[4] = rsqrtf((sm[0]+sm[1]+sm[2]+sm[3]) * (1.0f/DMODEL) + EPS);
  __syncthreads();
  float r = sm[4];
  float4 wv = ((const float4*)w)[threadIdx.x];
  ushort4 ob;
  ob.x = f2bf(v.x*r*wv.x); ob.y = f2bf(v.y*r*wv.y);
  ob.z = f2bf(v.z*r*wv.z); ob.w = f2bf(v.w*r*wv.w);
  ((ushort4*)(o + row * DMODEL))[threadIdx.x] = ob;
}

// ------------- cast fp32 [K][N] -> bf16 transposed [N][dstStride] ------------
__global__ __launch_bounds__(256) void cast_t_k(const float* __restrict__ src,
                                                __hip_bfloat16* __restrict__ dst,
                                                int N, int dstStride){
  __shared__ float t[32][33];
  int n0 = blockIdx.x*32, k0 = blockIdx.y*32;
  int tx = threadIdx.x, ty = threadIdx.y;
  #pragma unroll
  for (int i = 0; i < 4; ++i)
    t[ty*4+i][tx] = src[(size_t)(k0+ty*4+i)*N + n0 + tx];
  __syncthreads();
  #pragma unroll
  for (int i = 0; i < 4; ++i)
    dst[(size_t)(n0+ty*4+i)*dstStride + k0 + tx] = __float2bfloat16(t[tx][ty*4+i]);
}

__global__ __launch_bounds__(256) void bias_cat_k(const float* __restrict__ bq,
                                                  const float* __restrict__ bk,
                                                  const float* __restrict__ bv,
                                                  float* __restrict__ bqkv){
  int t = blockIdx.x*256 + threadIdx.x;   // 0..1535
  float v = (t < 1024) ? bq[t] : (t < 1280 ? bk[t-1024] : bv[t-1280]);
  bqkv[t] = v;
}

// ---------------- bf16 MFMA GEMM (m97 structure) -----------------------------
// C[M,N] = A[M,K](bf16) @ W[K,N], W supplied transposed: Wt[N][K] bf16.
// 128x128 tile, BK=32, 256 threads = 4 waves (2x2), 4x4 16x16 tiles per wave.
// EPI: 0 = +bias -> fp32 ; 1 = +bias,gelu -> bf16 ; 2 = +bias,+res -> fp32
template<int EPI>
__global__ __launch_bounds__(256) void mgemm_k(const __hip_bfloat16* __restrict__ A,
                                               const __hip_bfloat16* __restrict__ Wt,
                                               const float* __restrict__ bias,
                                               const float* __restrict__ res,
                                               float* __restrict__ Cf,
                                               __hip_bfloat16* __restrict__ Cb,
                                               int N, int K){
  __shared__ __align__(16) __hip_bfloat16 As[128*32];
  __shared__ __align__(16) __hip_bfloat16 Bs[128*32];
  const int tid = threadIdx.x;
  const int wv = tid >> 6, l = tid & 63;
  const int bm = blockIdx.y * 128, bn = blockIdx.x * 128;
  const int wm = (wv >> 1) * 64, wn = (wv & 1) * 64;

  // staging map: wave wv stages rows [32wv..32wv+31]; lane l -> row +l/4, k (l%4)*8
  const __hip_bfloat16* Ag = A  + (size_t)(bm + wv*32 + (l>>2))*K + (l&3)*8;
  const __hip_bfloat16* Bg = Wt + (size_t)(bn + wv*32 + (l>>2))*K + (l&3)*8;
  __hip_bfloat16* Asl = As + (wv*32)*32 + l*8;
  __hip_bfloat16* Bsl = Bs + (wv*32)*32 + l*8;

  f4_t acc[4][4] = {};

  for (int k0 = 0; k0 < K; k0 += 32){
    __syncthreads();
    __builtin_amdgcn_global_load_lds((const AS1 void*)(Ag + k0),        (AS3 void*)(Asl),          16, 0, 0);
    __builtin_amdgcn_global_load_lds((const AS1 void*)(Ag + 16*(size_t)K + k0), (AS3 void*)(Asl + 16*32), 16, 0, 0);
    __builtin_amdgcn_global_load_lds((const AS1 void*)(Bg + k0),        (AS3 void*)(Bsl),          16, 0, 0);
    __builtin_amdgcn_global_load_lds((const AS1 void*)(Bg + 16*(size_t)K + k0), (AS3 void*)(Bsl + 16*32), 16, 0, 0);
    __syncthreads();
    bf8_t af[4], bfr[4];
    #pragma unroll
    for (int mi = 0; mi < 4; ++mi)
      af[mi] = *(const bf8_t*)(As + (wm + mi*16 + (l & 15))*32 + (l>>4)*8);
    #pragma unroll
    for (int ni = 0; ni < 4; ++ni)
      bfr[ni] = *(const bf8_t*)(Bs + (wn + ni*16 + (l & 15))*32 + (l>>4)*8);
    #pragma unroll
    for (int mi = 0; mi < 4; ++mi)
      #pragma unroll
      for (int ni = 0; ni < 4; ++ni)
        acc[mi][ni] = __builtin_amdgcn_mfma_f32_16x16x32_bf16(af[mi], bfr[ni], acc[mi][ni], 0, 0, 0);
  }

  // C/D layout: col = lane&15, row = (lane>>4)*4 + r
  const int q = l >> 4;
  #pragma unroll
  for (int ni = 0; ni < 4; ++ni){
    int col = bn + wn + ni*16 + (l & 15);
    float bb = bias[col];
    #pragma unroll
    for (int mi = 0; mi < 4; ++mi){
      #pragma unroll
      for (int r = 0; r < 4; ++r){
        int row = bm + wm + mi*16 + q*4 + r;
        size_t off = (size_t)row * N + col;
        float v = acc[mi][ni][r] + bb;
        if (EPI == 1)      Cb[off] = __float2bfloat16(gelu_f(v));
        else if (EPI == 2) Cf[off] = v + res[off];
        else               Cf[off] = v;
      }
    }
  }
}

// ---------------- per-head RMSNorm + RoPE, one wave per (s,b,head) -----------
__global__ __launch_bounds__(64) void rope_k(const float* __restrict__ in, const float* __restrict__ w,
                                             float* __restrict__ out, int nh, int col0, int stride){
  const int s = blockIdx.x;
  const int b = blockIdx.y / nh, hh = blockIdx.y % nh;
  const int lane = threadIdx.x;
  float v = in[((size_t)s * BATCH + b) * stride + col0 + hh*64 + lane];
  float ss = v * v;
  #pragma unroll
  for (int m = 32; m; m >>= 1) ss += __shfl_xor(ss, m);
  float r = rsqrtf(ss * (1.0f/64.0f) + EPS);
  v = v * r * w[lane];
  int i = lane & 31;
  float invf = powf(10000.0f, -((float)(2*i)) * (1.0f/64.0f));
  float ang = (float)s * invf;
  float c, sn;
  sincosf(ang, &sn, &c);
  float partner = __shfl_xor(v, 32);
  float rh = (lane < 32) ? -partner : partner;
  out[(((size_t)b * nh + hh) * S_LEN + s) * 64 + lane] = v * c + rh * sn;
}

// ---------------- flash attention, 64x64 tiles, fp32, bf16 out ---------------
__global__ __launch_bounds__(256) void attn_k(const float* __restrict__ Q, const float* __restrict__ Kc,
                                              const float* __restrict__ QKVt, __hip_bfloat16* __restrict__ AO){
  __shared__ float Qs[64][68];
  __shared__ float KVs[64][64];
  __shared__ float Ps[64][68];
  const int qb = blockIdx.x;
  const int bh = blockIdx.y;
  const int b = bh >> 4, h = bh & 15;
  const int kvh = h >> 2;
  const int tid = threadIdx.x;
  const int tx = tid & 15, ty = tid >> 4;
  const int lane = tid & 63, wvi = tid >> 6;

  const float* qp = Q + (((size_t)bh * S_LEN) + (size_t)qb*64) * 64;
  const float* kp = Kc + ((size_t)(b*NKV + kvh) * S_LEN) * 64;
  const float* vp = QKVt + 1280 + kvh*64;

  #pragma unroll
  for (int ii = 0; ii < 4; ++ii){
    int lin = tid + 256*ii;
    int r = lin >> 4, c4 = (lin & 15) * 4;
    *(float4*)&Qs[r][c4] = *(const float4*)(qp + r*64 + c4);
  }

  float o[4][4] = {};
  float m_i[4], l_i[4];
  #pragma unroll
  for (int i = 0; i < 4; ++i){ m_i[i] = -3.0e38f; l_i[i] = 0.0f; }

  for (int kt = 0; kt <= qb; ++kt){
    __syncthreads();
    #pragma unroll
    for (int ii = 0; ii < 4; ++ii){
      int d4 = 4 * (wvi + 4*ii);
      float4 kvv = *(const float4*)(kp + (size_t)(kt*64 + lane)*64 + d4);
      KVs[d4+0][lane] = kvv.x; KVs[d4+1][lane] = kvv.y;
      KVs[d4+2][lane] = kvv.z; KVs[d4+3][lane] = kvv.w;
    }
    __syncthreads();
    float s[4][4] = {};
    for (int kk = 0; kk < 64; ++kk){
      float4 bv = *(const float4*)&KVs[kk][tx*4];
      #pragma unroll
      for (int i = 0; i < 4; ++i){
        float a = Qs[ty*4+i][kk];
        s[i][0] += a*bv.x; s[i][1] += a*bv.y; s[i][2] += a*bv.z; s[i][3] += a*bv.w;
      }
    }
    const bool diag = (kt == qb);
    #pragma unroll
    for (int i = 0; i < 4; ++i)
      #pragma unroll
      for (int j = 0; j < 4; ++j){
        float vv = s[i][j] * ATT_SCALE;
        if (diag && (tx*4+j) > (ty*4+i)) vv = -1.0e30f;
        s[i][j] = vv;
      }
    float alpha[4];
    #pragma unroll
    for (int i = 0; i < 4; ++i){
      float mx = fmaxf(fmaxf(s[i][0], s[i][1]), fmaxf(s[i][2], s[i][3]));
      #pragma unroll
      for (int m = 1; m <= 8; m <<= 1) mx = fmaxf(mx, __shfl_xor(mx, m));
      mx = fmaxf(mx, m_i[i]);
      alpha[i] = __expf(m_i[i] - mx);
      m_i[i] = mx;
      float rs = 0.f;
      #pragma unroll
      for (int j = 0; j < 4; ++j){ s[i][j] = __expf(s[i][j] - mx); rs += s[i][j]; }
      #pragma unroll
      for (int m = 1; m <= 8; m <<= 1) rs += __shfl_xor(rs, m);
      l_i[i] = l_i[i] * alpha[i] + rs;
    }
    #pragma unroll
    for (int i = 0; i < 4; ++i)
      *(float4*)&Ps[ty*4+i][tx*4] = make_float4(s[i][0], s[i][1], s[i][2], s[i][3]);
    __syncthreads();
    #pragma unroll
    for (int ii = 0; ii < 4; ++ii){
      int lin = tid + 256*ii;
      int c = lin >> 4, d4 = (lin & 15)*4;
      *(float4*)&KVs[c][d4] = *(const float4*)(vp + ((size_t)(kt*64 + c)*BATCH + b) * 1536 + d4);
    }
    __syncthreads();
    #pragma unroll
    for (int i = 0; i < 4; ++i){
      o[i][0]*=alpha[i]; o[i][1]*=alpha[i]; o[i][2]*=alpha[i]; o[i][3]*=alpha[i];
    }
    for (int c = 0; c < 64; ++c){
      float4 vv = *(const float4*)&KVs[c][tx*4];
      #pragma unroll
      for (int i = 0; i < 4; ++i){
        float pp = Ps[ty*4+i][c];
        o[i][0] += pp*vv.x; o[i][1] += pp*vv.y; o[i][2] += pp*vv.z; o[i][3] += pp*vv.w;
      }
    }
  }
  #pragma unroll
  for (int i = 0; i < 4; ++i){
    int sg = qb*64 + ty*4 + i;
    float inv = 1.0f / l_i[i];
    ushort4 w4;
    w4.x = f2bf(o[i][0]*inv); w4.y = f2bf(o[i][1]*inv);
    w4.z = f2bf(o[i][2]*inv); w4.w = f2bf(o[i][3]*inv);
    *(ushort4*)(AO + ((size_t)sg * BATCH + b) * DMODEL + h*64 + tx*4) = w4;
  }
}

extern "C" void kernel_launch(void* const* d_in, const int* in_sizes, int n_in,
                              void* d_out, int out_size, void* d_ws, size_t ws_size,
                              hipStream_t stream){
  const float* x   = (const float*)d_in[0];
  const float* n1w = (const float*)d_in[1];
  const float* wq  = (const float*)d_in[2];
  const float* bq  = (const float*)d_in[3];
  const float* wk  = (const float*)d_in[4];
  const float* bk  = (const float*)d_in[5];
  const float* wv  = (const float*)d_in[6];
  const float* bv  = (const float*)d_in[7];
  const float* qnw = (const float*)d_in[8];
  const float* knw = (const float*)d_in[9];
  const float* wo  = (const float*)d_in[10];
  const float* bo  = (const float*)d_in[11];
  const float* n2w = (const float*)d_in[12];
  const float* w1  = (const float*)d_in[13];
  const float* b1  = (const float*)d_in[14];
  const float* w2  = (const float*)d_in[15];
  const float* b2  = (const float*)d_in[16];
  float* out = (float*)d_out;

  char* p = (char*)d_ws;
  auto carve = [&](size_t bytes)->char*{ char* r = p; p += (bytes + 255) & ~(size_t)255; return r; };
  __hip_bfloat16* h_bf   = (__hip_bfloat16*)carve((size_t)MROWS*DMODEL*2);
  __hip_bfloat16* ao_bf  = (__hip_bfloat16*)carve((size_t)MROWS*DMODEL*2);
  __hip_bfloat16* mid_bf = (__hip_bfloat16*)carve((size_t)MROWS*4096*2);
  __hip_bfloat16* wqkv_t = (__hip_bfloat16*)carve((size_t)1536*1024*2);
  __hip_bfloat16* wo_t   = (__hip_bfloat16*)carve((size_t)1024*1024*2);
  __hip_bfloat16* w1_t   = (__hip_bfloat16*)carve((size_t)4096*1024*2);
  __hip_bfloat16* w2_t   = (__hip_bfloat16*)carve((size_t)1024*4096*2);
  float* bqkv = (float*)carve(1536*4);
  float* qkvt = (float*)carve((size_t)MROWS*1536*4);
  float* q    = (float*)carve((size_t)BATCH*NH *S_LEN*64*4);
  float* kbuf = (float*)carve((size_t)BATCH*NKV*S_LEN*64*4);
  float* x1   = (float*)carve((size_t)MROWS*DMODEL*4);

  // weight prep (fp32 [K][N] -> bf16 [N][K])
  cast_t_k<<<dim3(32, 32), dim3(32,8), 0, stream>>>(wq, wqkv_t,               1024, 1024);
  cast_t_k<<<dim3( 8, 32), dim3(32,8), 0, stream>>>(wk, wqkv_t + 1024*1024,    256, 1024);
  cast_t_k<<<dim3( 8, 32), dim3(32,8), 0, stream>>>(wv, wqkv_t + 1280*1024,    256, 1024);
  cast_t_k<<<dim3(32, 32), dim3(32,8), 0, stream>>>(wo, wo_t,                 1024, 1024);
  cast_t_k<<<dim3(128,32), dim3(32,8), 0, stream>>>(w1, w1_t,                 4096, 1024);
  cast_t_k<<<dim3(32,128), dim3(32,8), 0, stream>>>(w2, w2_t,                 1024, 4096);
  bias_cat_k<<<6, 256, 0, stream>>>(bq, bk, bv, bqkv);

  rmsnorm_k<<<MROWS, 256, 0, stream>>>(x, n1w, h_bf);
  mgemm_k<0><<<dim3(1536/128, MROWS/128), 256, 0, stream>>>(h_bf, wqkv_t, bqkv, nullptr, qkvt, nullptr, 1536, 1024);
  rope_k<<<dim3(S_LEN, BATCH*NH),  64, 0, stream>>>(qkvt, qnw, q,    NH,  0,    1536);
  rope_k<<<dim3(S_LEN, BATCH*NKV), 64, 0, stream>>>(qkvt, knw, kbuf, NKV, 1024, 1536);
  attn_k<<<dim3(S_LEN/64, BATCH*NH), 256, 0, stream>>>(q, kbuf, qkvt, ao_bf);
  mgemm_k<2><<<dim3(DMODEL/128, MROWS/128), 256, 0, stream>>>(ao_bf, wo_t, bo, x, x1, nullptr, DMODEL, 1024);
  rmsnorm_k<<<MROWS, 256, 0, stream>>>(x1, n2w, h_bf);
  mgemm_k<1><<<dim3(4096/128, MROWS/128), 256, 0, stream>>>(h_bf, w1_t, b1, nullptr, nullptr, mid_bf, 4096, 1024);
  mgemm_k<2><<<dim3(DMODEL/128, MROWS/128), 256, 0, stream>>>(mid_bf, w2_t, b2, x1, out, nullptr, DMODEL, 4096);
}

// Round 4
// 452.656 us; speedup vs baseline: 3.8677x; 1.8524x over previous
//
#include <hip/hip_runtime.h>
#include <hip/hip_bf16.h>
#include <math.h>

#define S_LEN 2048
#define BATCH 2
#define DMODEL 1024
#define NH 16
#define NKV 4
#define HDIM 64
#define EPS 1e-5f
#define MROWS (S_LEN*BATCH)  // 4096
// attention scale folded into Q at rope time, including log2(e) so softmax uses exp2
#define QSCALE (0.03125f * 1.44269504088896f)

#define AS1 __attribute__((address_space(1)))
#define AS3 __attribute__((address_space(3)))

typedef __attribute__((ext_vector_type(8))) short bf8_t;
typedef __attribute__((ext_vector_type(4))) float f4_t;
typedef _Float16 __attribute__((ext_vector_type(8))) h8_t;
typedef _Float16 __attribute__((ext_vector_type(4))) h4_t;

// legacy K=16 f16 MFMA — canonical (no-underscore) spelling, known to host clang too
#define MFMA16(a,b,c) __builtin_amdgcn_mfma_f32_16x16x16f16(a,b,c,0,0,0)

__device__ __forceinline__ float exp2_fast(float x){ return __builtin_exp2f(x); }

__device__ __forceinline__ unsigned short f2bf(float f){
  __hip_bfloat16 b = __float2bfloat16(f);
  return __builtin_bit_cast(unsigned short, b);
}
__device__ __forceinline__ float gelu_f(float x){
  return 0.5f * x * (1.0f + erff(x * 0.7071067811865475f));
}

// ---------------- RMSNorm -> bf16 out: one block per row ---------------------
__global__ __launch_bounds__(256) void rmsnorm_k(const float* __restrict__ x,
                                                 const float* __restrict__ w,
                                                 __hip_bfloat16* __restrict__ o){
  size_t row = blockIdx.x;
  const float4* xr = (const float4*)(x + row * DMODEL);
  float4 v = xr[threadIdx.x];
  float ss = v.x*v.x + v.y*v.y + v.z*v.z + v.w*v.w;
  #pragma unroll
  for (int off = 32; off; off >>= 1) ss += __shfl_down(ss, off);
  __shared__ float sm[5];
  if ((threadIdx.x & 63) == 0) sm[threadIdx.x >> 6] = ss;
  __syncthreads();
  if (threadIdx.x == 0) sm[4] = rsqrtf((sm[0]+sm[1]+sm[2]+sm[3]) * (1.0f/DMODEL) + EPS);
  __syncthreads();
  float r = sm[4];
  float4 wv = ((const float4*)w)[threadIdx.x];
  ushort4 ob;
  ob.x = f2bf(v.x*r*wv.x); ob.y = f2bf(v.y*r*wv.y);
  ob.z = f2bf(v.z*r*wv.z); ob.w = f2bf(v.w*r*wv.w);
  ((ushort4*)(o + row * DMODEL))[threadIdx.x] = ob;
}

// ------------- cast fp32 [K][N] -> bf16 transposed [N][dstStride] ------------
__global__ __launch_bounds__(256) void cast_t_k(const float* __restrict__ src,
                                                __hip_bfloat16* __restrict__ dst,
                                                int N, int dstStride){
  __shared__ float t[32][33];
  int n0 = blockIdx.x*32, k0 = blockIdx.y*32;
  int tx = threadIdx.x, ty = threadIdx.y;
  #pragma unroll
  for (int i = 0; i < 4; ++i)
    t[ty*4+i][tx] = src[(size_t)(k0+ty*4+i)*N + n0 + tx];
  __syncthreads();
  #pragma unroll
  for (int i = 0; i < 4; ++i)
    dst[(size_t)(n0+ty*4+i)*dstStride + k0 + tx] = __float2bfloat16(t[tx][ty*4+i]);
}

__global__ __launch_bounds__(256) void bias_cat_k(const float* __restrict__ bq,
                                                  const float* __restrict__ bk,
                                                  const float* __restrict__ bv,
                                                  float* __restrict__ bqkv){
  int t = blockIdx.x*256 + threadIdx.x;
  float v = (t < 1024) ? bq[t] : (t < 1280 ? bk[t-1024] : bv[t-1280]);
  bqkv[t] = v;
}

// ---------------- bf16 MFMA GEMM (m97 structure) -----------------------------
template<int EPI>  // 0 = +bias->fp32 ; 1 = +bias,gelu->bf16 ; 2 = +bias,+res->fp32
__global__ __launch_bounds__(256) void mgemm_k(const __hip_bfloat16* __restrict__ A,
                                               const __hip_bfloat16* __restrict__ Wt,
                                               const float* __restrict__ bias,
                                               const float* __restrict__ res,
                                               float* __restrict__ Cf,
                                               __hip_bfloat16* __restrict__ Cb,
                                               int N, int K){
  __shared__ __align__(16) __hip_bfloat16 As[128*32];
  __shared__ __align__(16) __hip_bfloat16 Bs[128*32];
  const int tid = threadIdx.x;
  const int wv = tid >> 6, l = tid & 63;
  const int bm = blockIdx.y * 128, bn = blockIdx.x * 128;
  const int wm = (wv >> 1) * 64, wn = (wv & 1) * 64;

  const __hip_bfloat16* Ag = A  + (size_t)(bm + wv*32 + (l>>2))*K + (l&3)*8;
  const __hip_bfloat16* Bg = Wt + (size_t)(bn + wv*32 + (l>>2))*K + (l&3)*8;
  __hip_bfloat16* Asl = As + (wv*32)*32 + l*8;
  __hip_bfloat16* Bsl = Bs + (wv*32)*32 + l*8;

  f4_t acc[4][4] = {};

  for (int k0 = 0; k0 < K; k0 += 32){
    __syncthreads();
    __builtin_amdgcn_global_load_lds((const AS1 void*)(Ag + k0),        (AS3 void*)(Asl),          16, 0, 0);
    __builtin_amdgcn_global_load_lds((const AS1 void*)(Ag + 16*(size_t)K + k0), (AS3 void*)(Asl + 16*32), 16, 0, 0);
    __builtin_amdgcn_global_load_lds((const AS1 void*)(Bg + k0),        (AS3 void*)(Bsl),          16, 0, 0);
    __builtin_amdgcn_global_load_lds((const AS1 void*)(Bg + 16*(size_t)K + k0), (AS3 void*)(Bsl + 16*32), 16, 0, 0);
    __syncthreads();
    bf8_t af[4], bfr[4];
    #pragma unroll
    for (int mi = 0; mi < 4; ++mi)
      af[mi] = *(const bf8_t*)(As + (wm + mi*16 + (l & 15))*32 + (l>>4)*8);
    #pragma unroll
    for (int ni = 0; ni < 4; ++ni)
      bfr[ni] = *(const bf8_t*)(Bs + (wn + ni*16 + (l & 15))*32 + (l>>4)*8);
    #pragma unroll
    for (int mi = 0; mi < 4; ++mi)
      #pragma unroll
      for (int ni = 0; ni < 4; ++ni)
        acc[mi][ni] = __builtin_amdgcn_mfma_f32_16x16x32_bf16(af[mi], bfr[ni], acc[mi][ni], 0, 0, 0);
  }

  const int q = l >> 4;
  #pragma unroll
  for (int ni = 0; ni < 4; ++ni){
    int col = bn + wn + ni*16 + (l & 15);
    float bb = bias[col];
    #pragma unroll
    for (int mi = 0; mi < 4; ++mi){
      #pragma unroll
      for (int r = 0; r < 4; ++r){
        int row = bm + wm + mi*16 + q*4 + r;
        size_t off = (size_t)row * N + col;
        float v = acc[mi][ni][r] + bb;
        if (EPI == 1)      Cb[off] = __float2bfloat16(gelu_f(v));
        else if (EPI == 2) Cf[off] = v + res[off];
        else               Cf[off] = v;
      }
    }
  }
}

// ---------------- per-head RMSNorm + RoPE -> f16, one wave per (s,b,head) ----
__global__ __launch_bounds__(64) void rope_k(const float* __restrict__ in, const float* __restrict__ w,
                                             _Float16* __restrict__ out, int nh, int col0, int stride,
                                             float oscale){
  const int s = blockIdx.x;
  const int b = blockIdx.y / nh, hh = blockIdx.y % nh;
  const int lane = threadIdx.x;
  float v = in[((size_t)s * BATCH + b) * stride + col0 + hh*64 + lane];
  float ss = v * v;
  #pragma unroll
  for (int m = 32; m; m >>= 1) ss += __shfl_xor(ss, m);
  float r = rsqrtf(ss * (1.0f/64.0f) + EPS);
  v = v * r * w[lane];
  int i = lane & 31;
  float invf = powf(10000.0f, -((float)(2*i)) * (1.0f/64.0f));
  float ang = (float)s * invf;
  float c, sn;
  sincosf(ang, &sn, &c);
  float partner = __shfl_xor(v, 32);
  float rh = (lane < 32) ? -partner : partner;
  out[(((size_t)b * nh + hh) * S_LEN + s) * 64 + lane] = (_Float16)((v * c + rh * sn) * oscale);
}

// ---------------- V extract: qkvt fp32 [S,B,1536] -> Vt f16 [B*NKV][64][S] ---
__global__ __launch_bounds__(256) void vcast_k(const float* __restrict__ qkvt,
                                               _Float16* __restrict__ Vt){
  __shared__ float t[64][65];
  const int s0 = blockIdx.x * 64;
  const int bkv = blockIdx.y;
  const int b = bkv >> 2, kv = bkv & 3;
  const int tid = threadIdx.x;
  #pragma unroll
  for (int i = 0; i < 16; ++i){
    int idx = tid + 256*i;
    int sl = idx >> 6, d = idx & 63;
    t[d][sl] = qkvt[((size_t)(s0+sl)*BATCH + b)*1536 + 1280 + kv*64 + d];
  }
  __syncthreads();
  #pragma unroll
  for (int i = 0; i < 16; ++i){
    int idx = tid + 256*i;
    int d = idx >> 6, sl = idx & 63;
    Vt[((size_t)bkv*64 + d)*S_LEN + s0 + sl] = (_Float16)t[d][sl];
  }
}

// ---------------- MFMA flash attention -------------------------------------
// Per block: one (b,h), 64 q-rows. 4 waves, each owns 16 q-rows.
// S^T = K·Q^T  (C-frag: col=q-row, row=k-col)  -> softmax in regs ->
// P^T feeds PV directly as K=16 B-operand: O^T = V^T·P^T.
__global__ __launch_bounds__(256) void attn2_k(const _Float16* __restrict__ Q,
                                               const _Float16* __restrict__ K,
                                               const _Float16* __restrict__ Vt,
                                               __hip_bfloat16* __restrict__ AO){
  __shared__ __align__(16) _Float16 Ks[8*512];   // 8 chunks: (cc,dh), lane-major
  __shared__ __align__(16) _Float16 Vs[8*512];   // 8 chunks: (dd,cc32)
  const int bh = blockIdx.x;                 // b*16 + h
  const int qb = (gridDim.y - 1) - blockIdx.y;   // longest first
  const int b = bh >> 4, h = bh & 15;
  const int kvh = h >> 2;
  const int tid = threadIdx.x;
  const int w = tid >> 6, l = tid & 63;
  const int lr = l & 15, quad = l >> 4;

  const _Float16* qp = Q + ((size_t)bh * S_LEN + qb*64 + w*16 + lr) * 64;
  h8_t qf0 = *(const h8_t*)(qp + quad*8);
  h8_t qf1 = *(const h8_t*)(qp + 32 + quad*8);

  const _Float16* kbase = K  + (size_t)(b*NKV + kvh) * S_LEN * 64;
  const _Float16* vbase = Vt + (size_t)(b*NKV + kvh) * 64 * S_LEN;

  f4_t Od[4] = {};
  float m_i = -3.0e38f, l_i = 0.0f;

  for (int kt = 0; kt <= qb; ++kt){
    __syncthreads();
    // stage K (8 chunks) + Vt (8 chunks); wave w issues instrs [4w,4w+4)
    #pragma unroll
    for (int ii = 0; ii < 4; ++ii){
      int i = w*4 + ii;
      if (i < 8){
        int cc = i >> 1, dh = i & 1;
        const _Float16* src = kbase + (size_t)(kt*64 + cc*16 + lr)*64 + dh*32 + quad*8;
        __builtin_amdgcn_global_load_lds((const AS1 void*)src, (AS3 void*)(Ks + i*512), 16, 0, 0);
      } else {
        int j = i - 8;
        int dd = j >> 1, cc32 = j & 1;
        const _Float16* src = vbase + (size_t)(dd*16 + lr)*S_LEN + kt*64 + cc32*32 + quad*8;
        __builtin_amdgcn_global_load_lds((const AS1 void*)src, (AS3 void*)(Vs + j*512), 16, 0, 0);
      }
    }
    __syncthreads();

    const bool diag = (kt == qb);
    f4_t sc[4];
    #pragma unroll
    for (int nc2 = 0; nc2 < 4; ++nc2){
      if (diag && nc2 > w){
        sc[nc2][0] = -1.0e30f; sc[nc2][1] = -1.0e30f;
        sc[nc2][2] = -1.0e30f; sc[nc2][3] = -1.0e30f;
        continue;
      }
      f4_t a = {};
      h8_t k0 = *(const h8_t*)(Ks + (nc2*2+0)*512 + l*8);
      h8_t k1 = *(const h8_t*)(Ks + (nc2*2+1)*512 + l*8);
      a = __builtin_amdgcn_mfma_f32_16x16x32_f16(k0, qf0, a, 0, 0, 0);
      a = __builtin_amdgcn_mfma_f32_16x16x32_f16(k1, qf1, a, 0, 0, 0);
      if (diag && nc2 == w){
        #pragma unroll
        for (int r = 0; r < 4; ++r)
          if (quad*4 + r > lr) a[r] = -1.0e30f;
      }
      sc[nc2] = a;
    }

    // online softmax; q-row = lr, k-index spread over quads -> 2 shuffles
    float mx = sc[0][0];
    #pragma unroll
    for (int nc2 = 0; nc2 < 4; ++nc2)
      #pragma unroll
      for (int r = 0; r < 4; ++r) mx = fmaxf(mx, sc[nc2][r]);
    mx = fmaxf(mx, __shfl_xor(mx, 16));
    mx = fmaxf(mx, __shfl_xor(mx, 32));
    float nm = fmaxf(mx, m_i);
    float alpha = exp2_fast(m_i - nm);
    m_i = nm;
    float rs = 0.0f;
    h4_t pf[4];
    #pragma unroll
    for (int nc2 = 0; nc2 < 4; ++nc2)
      #pragma unroll
      for (int r = 0; r < 4; ++r){
        float e = exp2_fast(sc[nc2][r] - nm);
        rs += e;
        pf[nc2][r] = (_Float16)e;
      }
    rs += __shfl_xor(rs, 16);
    rs += __shfl_xor(rs, 32);
    l_i = l_i * alpha + rs;
    #pragma unroll
    for (int dd = 0; dd < 4; ++dd)
      #pragma unroll
      for (int r = 0; r < 4; ++r) Od[dd][r] *= alpha;

    // O^T += V^T · P^T
    #pragma unroll
    for (int dd = 0; dd < 4; ++dd)
      #pragma unroll
      for (int nc2 = 0; nc2 < 4; ++nc2){
        if (diag && nc2 > w) continue;
        h4_t vf = *(const h4_t*)(Vs + (dd*2 + (nc2>>1))*512
                                 + (((nc2&1)*2 + (quad>>1))*16 + lr)*8 + (quad&1)*4);
        Od[dd] = MFMA16(vf, pf[nc2], Od[dd]);
      }
  }

  float inv = 1.0f / l_i;
  #pragma unroll
  for (int dd = 0; dd < 4; ++dd){
    ushort4 w4;
    w4.x = f2bf(Od[dd][0]*inv); w4.y = f2bf(Od[dd][1]*inv);
    w4.z = f2bf(Od[dd][2]*inv); w4.w = f2bf(Od[dd][3]*inv);
    size_t sg = (size_t)qb*64 + w*16 + lr;
    *(ushort4*)(AO + (sg*BATCH + b)*DMODEL + h*64 + dd*16 + quad*4) = w4;
  }
}

extern "C" void kernel_launch(void* const* d_in, const int* in_sizes, int n_in,
                              void* d_out, int out_size, void* d_ws, size_t ws_size,
                              hipStream_t stream){
  const float* x   = (const float*)d_in[0];
  const float* n1w = (const float*)d_in[1];
  const float* wq  = (const float*)d_in[2];
  const float* bq  = (const float*)d_in[3];
  const float* wk  = (const float*)d_in[4];
  const float* bk  = (const float*)d_in[5];
  const float* wv  = (const float*)d_in[6];
  const float* bv  = (const float*)d_in[7];
  const float* qnw = (const float*)d_in[8];
  const float* knw = (const float*)d_in[9];
  const float* wo  = (const float*)d_in[10];
  const float* bo  = (const float*)d_in[11];
  const float* n2w = (const float*)d_in[12];
  const float* w1  = (const float*)d_in[13];
  const float* b1  = (const float*)d_in[14];
  const float* w2  = (const float*)d_in[15];
  const float* b2  = (const float*)d_in[16];
  float* out = (float*)d_out;

  char* p = (char*)d_ws;
  auto carve = [&](size_t bytes)->char*{ char* r = p; p += (bytes + 255) & ~(size_t)255; return r; };
  __hip_bfloat16* h_bf   = (__hip_bfloat16*)carve((size_t)MROWS*DMODEL*2);
  __hip_bfloat16* ao_bf  = (__hip_bfloat16*)carve((size_t)MROWS*DMODEL*2);
  __hip_bfloat16* mid_bf = (__hip_bfloat16*)carve((size_t)MROWS*4096*2);
  __hip_bfloat16* wqkv_t = (__hip_bfloat16*)carve((size_t)1536*1024*2);
  __hip_bfloat16* wo_t   = (__hip_bfloat16*)carve((size_t)1024*1024*2);
  __hip_bfloat16* w1_t   = (__hip_bfloat16*)carve((size_t)4096*1024*2);
  __hip_bfloat16* w2_t   = (__hip_bfloat16*)carve((size_t)1024*4096*2);
  float* bqkv = (float*)carve(1536*4);
  float* qkvt = (float*)carve((size_t)MROWS*1536*4);
  _Float16* q_f  = (_Float16*)carve((size_t)BATCH*NH *S_LEN*64*2);
  _Float16* k_f  = (_Float16*)carve((size_t)BATCH*NKV*S_LEN*64*2);
  _Float16* vt_f = (_Float16*)carve((size_t)BATCH*NKV*64*S_LEN*2);
  float* x1   = (float*)carve((size_t)MROWS*DMODEL*4);

  cast_t_k<<<dim3(32, 32), dim3(32,8), 0, stream>>>(wq, wqkv_t,               1024, 1024);
  cast_t_k<<<dim3( 8, 32), dim3(32,8), 0, stream>>>(wk, wqkv_t + 1024*1024,    256, 1024);
  cast_t_k<<<dim3( 8, 32), dim3(32,8), 0, stream>>>(wv, wqkv_t + 1280*1024,    256, 1024);
  cast_t_k<<<dim3(32, 32), dim3(32,8), 0, stream>>>(wo, wo_t,                 1024, 1024);
  cast_t_k<<<dim3(128,32), dim3(32,8), 0, stream>>>(w1, w1_t,                 4096, 1024);
  cast_t_k<<<dim3(32,128), dim3(32,8), 0, stream>>>(w2, w2_t,                 1024, 4096);
  bias_cat_k<<<6, 256, 0, stream>>>(bq, bk, bv, bqkv);

  rmsnorm_k<<<MROWS, 256, 0, stream>>>(x, n1w, h_bf);
  mgemm_k<0><<<dim3(1536/128, MROWS/128), 256, 0, stream>>>(h_bf, wqkv_t, bqkv, nullptr, qkvt, nullptr, 1536, 1024);
  rope_k<<<dim3(S_LEN, BATCH*NH),  64, 0, stream>>>(qkvt, qnw, q_f, NH,  0,    1536, QSCALE);
  rope_k<<<dim3(S_LEN, BATCH*NKV), 64, 0, stream>>>(qkvt, knw, k_f, NKV, 1024, 1536, 1.0f);
  vcast_k<<<dim3(S_LEN/64, BATCH*NKV), 256, 0, stream>>>(qkvt, vt_f);
  attn2_k<<<dim3(BATCH*NH, S_LEN/64), 256, 0, stream>>>(q_f, k_f, vt_f, ao_bf);
  mgemm_k<2><<<dim3(DMODEL/128, MROWS/128), 256, 0, stream>>>(ao_bf, wo_t, bo, x, x1, nullptr, DMODEL, 1024);
  rmsnorm_k<<<MROWS, 256, 0, stream>>>(x1, n2w, h_bf);
  mgemm_k<1><<<dim3(4096/128, MROWS/128), 256, 0, stream>>>(h_bf, w1_t, b1, nullptr, nullptr, mid_bf, 4096, 1024);
  mgemm_k<2><<<dim3(DMODEL/128, MROWS/128), 256, 0, stream>>>(mid_bf, w2_t, b2, x1, out, nullptr, DMODEL, 4096);
}